// Round 6
// baseline (512.290 us; speedup 1.0000x reference)
//
#include <hip/hip_runtime.h>

#define HW 64
#define CIN 256
#define OC1 128
#define NJ 49
#define KZ 8                 // K-split: each conv1 block does 32 ic x 49 taps
#define CELLS 56             // shorts per (row,col) cell: 32 ic + 24 pad (112B, 16B-mult)
#define CELLW 28             // words per cell (stride 28 mod 32 -> 8 distinct write banks)
#define BUFW (2 * 80 * CELLW)   // 4480 words = 17,920 B per buffer

typedef short bf16x8 __attribute__((ext_vector_type(8)));
typedef float f32x4 __attribute__((ext_vector_type(4)));

__device__ __forceinline__ unsigned f2bf_pack(float a, float b) {
    unsigned ua = __float_as_uint(a);
    ua += 0x7FFF + ((ua >> 16) & 1);
    unsigned ub = __float_as_uint(b);
    ub += 0x7FFF + ((ub >> 16) & 1);
    return (ua >> 16) | (ub & 0xFFFF0000u);
}

__device__ __forceinline__ unsigned short f2bf(float a) {
    unsigned u = __float_as_uint(a);
    u += 0x7FFF + ((u >> 16) & 1);
    return (unsigned short)(u >> 16);
}

// ---------------------------------------------------------------------------
// w1 fp32 [128 oc][256 ic][49 tap] -> w1t bf16 [49][128 oc][256 ic]
// ---------------------------------------------------------------------------
__global__ __launch_bounds__(256) void wtrans_kernel(const float* __restrict__ w1,
                                                     unsigned short* __restrict__ w1t) {
    __shared__ float ws[12544];     // [ic 256][tap 49]
    const int oc = blockIdx.x;
    const float4* src = (const float4*)(w1 + (size_t)oc * 12544);
    for (int f = threadIdx.x; f < 3136; f += 256)
        *(float4*)&ws[4 * f] = src[f];
    __syncthreads();
    for (int k = threadIdx.x; k < 12544; k += 256) {
        int tap = k >> 8, ic = k & 255;   // stride 49 mod 32 = 17: conflict-free
        w1t[((size_t)tap * 128 + oc) * 256 + ic] = f2bf(ws[ic * 49 + tap]);
    }
}

// ---------------------------------------------------------------------------
// conv1 implicit GEMM, bf16 MFMA 16x16x32, KZ=8.
// grid (32 hp, 8 kz, 4 b) = 1024 blocks (hp fastest: same-kz blocks adjacent
// -> same-XCD L2 weight locality); block 256 = 4 waves; wave 64 oc x 64 px.
// R3-style staging: global loads ISSUEd at u-start into regs (packed uint2),
// LDS WRITE after the tap loop into the other buffer; 1 barrier per u.
// Weight fragments software-pipelined 1 tap ahead (ping-pong regs).
// P bf16 [kz][b][oc][h][w] partials.
// ---------------------------------------------------------------------------
__global__ __launch_bounds__(256, 4) void conv1_mfma_kernel(
    const float* __restrict__ x, const unsigned short* __restrict__ w1t,
    unsigned short* __restrict__ P)
{
    __shared__ unsigned xs[2 * BUFW];   // 35,840 B

    const int hp = blockIdx.x, kz = blockIdx.y, b = blockIdx.z;
    const int h0 = hp * 2;
    const int t = threadIdx.x;
    const int lane = t & 63, wv = t >> 6;
    const int oc_off = (wv & 1) * 64;
    const int ri = wv >> 1;             // wave-uniform pixel row (0/1)
    const int l15 = lane & 15, quad = lane >> 4;

    f32x4 acc[4][4];
    #pragma unroll
    for (int i = 0; i < 4; ++i)
        #pragma unroll
        for (int j = 0; j < 4; ++j) acc[i][j] = (f32x4){0.f, 0.f, 0.f, 0.f};

    const float* xb = x + ((size_t)b * CIN + kz * 32) * 4096;
    const unsigned short* wbase = w1t + (size_t)(oc_off + l15) * 256 + kz * 32 + quad * 8;

    // 5 slots/thread: f = t + 256*i in [0,1280) -> (row 2, icq 8, col 80)
    uint2 pk[5];

    auto ISSUE = [&](int u) {           // global loads -> packed regs
        #pragma unroll
        for (int i = 0; i < 5; ++i) {
            int f = t + i * 256;
            int row = f / 640, rem = f - row * 640;
            int icq = rem / 80, col = rem - icq * 80;
            int r = h0 + row + 2 * u - 6;
            int c = col - 8;
            float v0 = 0.f, v1 = 0.f, v2 = 0.f, v3 = 0.f;
            if ((unsigned)r < 64u && (unsigned)c < 64u) {
                const float* p = xb + (size_t)(4 * icq) * 4096 + r * 64 + c;
                v0 = p[0]; v1 = p[4096]; v2 = p[8192]; v3 = p[12288];
            }
            pk[i] = make_uint2(f2bf_pack(v0, v1), f2bf_pack(v2, v3));
        }
    };
    auto WRITE = [&](unsigned* buf) {    // regs -> LDS (b64 per slot)
        #pragma unroll
        for (int i = 0; i < 5; ++i) {
            int f = t + i * 256;
            int row = f / 640, rem = f - row * 640;
            int icq = rem / 80, col = rem - icq * 80;
            *(uint2*)&buf[(row * 80 + col) * CELLW + 2 * icq] = pk[i];
        }
    };

    bf16x8 wfA[4], wfB[4];
    auto ldwf = [&](int s, bf16x8* d) {  // s = tap index (K=32 per tap)
        const unsigned short* wp = wbase + (size_t)s * (128 * 256);
        #pragma unroll
        for (int of = 0; of < 4; ++of)
            d[of] = *(const bf16x8*)(wp + of * (16 * 256));
    };

    ISSUE(0);
    WRITE(&xs[0]);
    ldwf(0, wfA);
    __syncthreads();

    for (int u = 0; u < 7; ++u) {
        unsigned* cur = &xs[(u & 1) * BUFW];
        if (u < 6) ISSUE(u + 1);         // loads fly under the tap loop

        #pragma unroll
        for (int v = 0; v < 7; ++v) {
            const int s = u * 7 + v;
            const int sp = (s < 48) ? s + 1 : 48;
            if (s & 1) ldwf(sp, wfA); else ldwf(sp, wfB);
            const bf16x8* cw = (s & 1) ? wfB : wfA;

            bf16x8 xf[4];
            #pragma unroll
            for (int pf = 0; pf < 4; ++pf) {
                const int scol = pf * 16 + l15 + 2 * v + 2;
                xf[pf] = *(const bf16x8*)((const unsigned short*)cur
                           + (ri * 80 + scol) * CELLS + quad * 8);
            }
            #pragma unroll
            for (int of = 0; of < 4; ++of)
                #pragma unroll
                for (int pf = 0; pf < 4; ++pf)
                    acc[of][pf] = __builtin_amdgcn_mfma_f32_16x16x32_bf16(
                        cw[of], xf[pf], acc[of][pf], 0, 0, 0);
        }

        if (u < 6) WRITE(&xs[((u + 1) & 1) * BUFW]);
        __syncthreads();
    }

    unsigned short* Pb = P + (size_t)(kz * 4 + b) * (128 * 4096) + (size_t)(h0 + ri) * 64;
    #pragma unroll
    for (int of = 0; of < 4; ++of) {
        const int oc = oc_off + of * 16 + quad * 4;
        #pragma unroll
        for (int pf = 0; pf < 4; ++pf) {
            const int w = pf * 16 + l15;
            #pragma unroll
            for (int reg = 0; reg < 4; ++reg)
                Pb[(size_t)(oc + reg) * 4096 + w] = f2bf(acc[of][pf][reg]);
        }
    }
}

// ---------------------------------------------------------------------------
// FUSED: conv2 (1x1, 128->49) + b2 + softmax + 49-tap dilated gather.
// grid (64 h, 4 b) = 256 blocks; block 512. Phase 1: reduce KZ bf16 partials
// + b1 -> k1s. Phase 2: conv2 j-tiled -> k2s. Phase 3: softmax -> as[] (LDS).
// Phase 4: gather 256 c in 4 passes (R5 tiling: thread = 4 w x 2 ch).
// ---------------------------------------------------------------------------
__global__ __launch_bounds__(512, 2) void conv2_gather_kernel(
    const unsigned short* __restrict__ P, const float* __restrict__ w2,
    const float* __restrict__ b2, const float* __restrict__ b1,
    const float* __restrict__ x, float* __restrict__ out)
{
    __shared__ float k1s[64 * 140];   // 35,840 B
    __shared__ float k2s[64 * 56];    // 14,336 B
    __shared__ float as[NJ * 64];     // 12,544 B  (total 62,720 <= 64K)
    const int h = blockIdx.x, b = blockIdx.y;
    const int t = threadIdx.x;

    for (int f = t; f < OC1 * 64; f += 512) {
        int w = f & 63, oc = f >> 6;
        float s = b1[oc];
        #pragma unroll
        for (int kzi = 0; kzi < KZ; ++kzi) {
            unsigned u = P[(((size_t)(kzi * 4 + b) * 128 + oc) * 64 + h) * 64 + w];
            s += __uint_as_float(u << 16);
        }
        k1s[w * 140 + oc] = s;
    }
    __syncthreads();

    const int w = t & 63, jg = t >> 6;
    float accj[7];
    if (jg < 7) {
        #pragma unroll
        for (int jj = 0; jj < 7; ++jj) accj[jj] = b2[7 * jg + jj];
        const float4* kv = (const float4*)&k1s[w * 140];
        for (int oc4 = 0; oc4 < 32; ++oc4) {
            float4 v = kv[oc4];
            #pragma unroll
            for (int jj = 0; jj < 7; ++jj) {
                const float* wr = w2 + (size_t)(7 * jg + jj) * OC1 + 4 * oc4;
                accj[jj] += v.x * wr[0] + v.y * wr[1] + v.z * wr[2] + v.w * wr[3];
            }
        }
        #pragma unroll
        for (int jj = 0; jj < 7; ++jj) k2s[w * 56 + 7 * jg + jj] = accj[jj];
    } else {
        #pragma unroll
        for (int j = 49; j < 56; ++j) k2s[w * 56 + j] = -1e30f;
    }
    __syncthreads();

    float4 vv[13];
    const float4* k2v = (const float4*)&k2s[w * 56];
    float m = -1e30f;
    #pragma unroll
    for (int i = 0; i < 13; ++i) {
        vv[i] = k2v[i];
        m = fmaxf(m, fmaxf(fmaxf(vv[i].x, vv[i].y), fmaxf(vv[i].z, vv[i].w)));
    }
    float s = 0.f;
    #pragma unroll
    for (int i = 0; i < 13; ++i) {
        s += __expf(vv[i].x - m) + __expf(vv[i].y - m)
           + __expf(vv[i].z - m) + __expf(vv[i].w - m);
    }
    const float inv = 1.f / s;
    if (jg < 7) {
        #pragma unroll
        for (int jj = 0; jj < 7; ++jj)
            as[(7 * jg + jj) * 64 + w] = __expf(accj[jj] - m) * inv;
    }
    __syncthreads();

    // gather: thread = (wp 16) x (cs 32); 4 passes cover 256 channels.
    const int wp = t & 15, cs = t >> 4;
    const int w0 = wp * 4;
    float* outb = out + (size_t)b * CIN * 4096 + (size_t)h * 64 + w0;

    for (int pass = 0; pass < 4; ++pass) {
        const int c0 = pass * 64 + cs * 2;
        const float* xb = x + (size_t)(b * CIN + c0) * 4096;
        float ac[2][4];
        #pragma unroll
        for (int c = 0; c < 2; ++c)
            #pragma unroll
            for (int wi = 0; wi < 4; ++wi) ac[c][wi] = 0.f;

        #pragma unroll
        for (int u = 0; u < 7; ++u) {
            const int row = h + 2 * u - 6;
            if ((unsigned)row >= 64u) continue;
            float xr[2][20];
            #pragma unroll
            for (int c = 0; c < 2; ++c) {
                const float4* rp = (const float4*)(xb + (size_t)c * 4096 + row * 64);
                #pragma unroll
                for (int j = 0; j < 5; ++j) {
                    const int i4 = wp - 2 + j;
                    float4 g = make_float4(0.f, 0.f, 0.f, 0.f);
                    if ((unsigned)i4 < 16u) g = rp[i4];
                    xr[c][4 * j + 0] = g.x; xr[c][4 * j + 1] = g.y;
                    xr[c][4 * j + 2] = g.z; xr[c][4 * j + 3] = g.w;
                }
            }
            #pragma unroll
            for (int v = 0; v < 7; ++v) {
                const float4 a4 = *(const float4*)&as[(u * 7 + v) * 64 + w0];
                const float av[4] = {a4.x, a4.y, a4.z, a4.w};
                #pragma unroll
                for (int wi = 0; wi < 4; ++wi)
                    #pragma unroll
                    for (int c = 0; c < 2; ++c)
                        ac[c][wi] += av[wi] * xr[c][wi + 2 * v + 2];
            }
        }
        #pragma unroll
        for (int c = 0; c < 2; ++c) {
            float4 st = make_float4(ac[c][0], ac[c][1], ac[c][2], ac[c][3]);
            *(float4*)&outb[(size_t)(c0 + c) * 4096] = st;
        }
    }
}

// ---------------------------------------------------------------------------
// ws: w1t bf16 3,211,264 B | P bf16 [8][4][128][4096] = 33,554,432 B (~36.8 MB)
// ---------------------------------------------------------------------------
extern "C" void kernel_launch(void* const* d_in, const int* in_sizes, int n_in,
                              void* d_out, int out_size, void* d_ws, size_t ws_size,
                              hipStream_t stream) {
    const float* x  = (const float*)d_in[0];
    const float* w1 = (const float*)d_in[1];
    const float* b1 = (const float*)d_in[2];
    const float* w2 = (const float*)d_in[3];
    const float* b2 = (const float*)d_in[4];
    float* out = (float*)d_out;

    unsigned short* w1t = (unsigned short*)d_ws;
    unsigned short* P   = (unsigned short*)((char*)d_ws + 3211264);

    wtrans_kernel<<<128, 256, 0, stream>>>(w1, w1t);
    conv1_mfma_kernel<<<dim3(32, KZ, 4), 256, 0, stream>>>(x, w1t, P);
    conv2_gather_kernel<<<dim3(HW, 4), 512, 0, stream>>>(P, w2, b2, b1, x, out);
}

// Round 7
// 385.363 us; speedup vs baseline: 1.3294x; 1.3294x over previous
//
#include <hip/hip_runtime.h>

#define HW 64
#define CIN 256
#define OC1 128
#define NJ 49
#define KZ 8                 // K-split: each conv1 block does 32 ic x 49 taps
#define CELLS 56             // shorts per (row,col) cell: 32 ic + 24 pad (112B, 16B-mult)
#define CELLW 28             // words per cell (stride 28 mod 32 -> 8 distinct write banks)
#define BUFW (2 * 80 * CELLW)   // 4480 words = 17,920 B per buffer

typedef short bf16x8 __attribute__((ext_vector_type(8)));
typedef float f32x4 __attribute__((ext_vector_type(4)));

__device__ __forceinline__ unsigned f2bf_pack(float a, float b) {
    unsigned ua = __float_as_uint(a);
    ua += 0x7FFF + ((ua >> 16) & 1);
    unsigned ub = __float_as_uint(b);
    ub += 0x7FFF + ((ub >> 16) & 1);
    return (ua >> 16) | (ub & 0xFFFF0000u);
}

__device__ __forceinline__ unsigned short f2bf(float a) {
    unsigned u = __float_as_uint(a);
    u += 0x7FFF + ((u >> 16) & 1);
    return (unsigned short)(u >> 16);
}

// ---------------------------------------------------------------------------
// w1 fp32 [128 oc][256 ic][49 tap] -> w1t bf16 [49][128 oc][256 ic]
// ---------------------------------------------------------------------------
__global__ __launch_bounds__(256) void wtrans_kernel(const float* __restrict__ w1,
                                                     unsigned short* __restrict__ w1t) {
    __shared__ float ws[12544];     // [ic 256][tap 49]
    const int oc = blockIdx.x;
    const float4* src = (const float4*)(w1 + (size_t)oc * 12544);
    for (int f = threadIdx.x; f < 3136; f += 256)
        *(float4*)&ws[4 * f] = src[f];
    __syncthreads();
    for (int k = threadIdx.x; k < 12544; k += 256) {
        int tap = k >> 8, ic = k & 255;   // stride 49 mod 32 = 17: conflict-free
        w1t[((size_t)tap * 128 + oc) * 256 + ic] = f2bf(ws[ic * 49 + tap]);
    }
}

// ---------------------------------------------------------------------------
// conv1 implicit GEMM, bf16 MFMA 16x16x32, KZ=8.
// grid (32 hp, 8 kz, 4 b) = 1024 blocks; block 256 = 4 waves; wave 64oc x 64px.
// Staging: global loads ISSUEd at u-start into regs (packed uint2), LDS WRITE
// after the tap loop into the other buffer; 1 barrier per u. Weight fragments
// ping-pong prefetched 1 tap ahead.
// NOTE: NO min-waves in launch_bounds — R6's (256,4) capped VGPR at 128 and
// spilled the 64-reg accumulator to scratch (1 GB WRITE_SIZE, 3x slower).
// P bf16 [kz][b][oc][h][w] partials.
// ---------------------------------------------------------------------------
__global__ __launch_bounds__(256) void conv1_mfma_kernel(
    const float* __restrict__ x, const unsigned short* __restrict__ w1t,
    unsigned short* __restrict__ P)
{
    __shared__ unsigned xs[2 * BUFW];   // 35,840 B

    const int hp = blockIdx.x, kz = blockIdx.y, b = blockIdx.z;
    const int h0 = hp * 2;
    const int t = threadIdx.x;
    const int lane = t & 63, wv = t >> 6;
    const int oc_off = (wv & 1) * 64;
    const int ri = wv >> 1;             // wave-uniform pixel row (0/1)
    const int l15 = lane & 15, quad = lane >> 4;

    f32x4 acc[4][4];
    #pragma unroll
    for (int i = 0; i < 4; ++i)
        #pragma unroll
        for (int j = 0; j < 4; ++j) acc[i][j] = (f32x4){0.f, 0.f, 0.f, 0.f};

    const float* xb = x + ((size_t)b * CIN + kz * 32) * 4096;
    const unsigned short* wbase = w1t + (size_t)(oc_off + l15) * 256 + kz * 32 + quad * 8;

    // 5 slots/thread: f = t + 256*i in [0,1280) -> (row 2, icq 8, col 80)
    uint2 pk[5];

    auto ISSUE = [&](int u) {           // global loads -> packed regs
        #pragma unroll
        for (int i = 0; i < 5; ++i) {
            int f = t + i * 256;
            int row = f / 640, rem = f - row * 640;
            int icq = rem / 80, col = rem - icq * 80;
            int r = h0 + row + 2 * u - 6;
            int c = col - 8;
            float v0 = 0.f, v1 = 0.f, v2 = 0.f, v3 = 0.f;
            if ((unsigned)r < 64u && (unsigned)c < 64u) {
                const float* p = xb + (size_t)(4 * icq) * 4096 + r * 64 + c;
                v0 = p[0]; v1 = p[4096]; v2 = p[8192]; v3 = p[12288];
            }
            pk[i] = make_uint2(f2bf_pack(v0, v1), f2bf_pack(v2, v3));
        }
    };
    auto WRITE = [&](unsigned* buf) {    // regs -> LDS (b64 per slot)
        #pragma unroll
        for (int i = 0; i < 5; ++i) {
            int f = t + i * 256;
            int row = f / 640, rem = f - row * 640;
            int icq = rem / 80, col = rem - icq * 80;
            *(uint2*)&buf[(row * 80 + col) * CELLW + 2 * icq] = pk[i];
        }
    };

    bf16x8 wfA[4], wfB[4];
    auto ldwf = [&](int s, bf16x8* d) {  // s = tap index (K=32 per tap)
        const unsigned short* wp = wbase + (size_t)s * (128 * 256);
        #pragma unroll
        for (int of = 0; of < 4; ++of)
            d[of] = *(const bf16x8*)(wp + of * (16 * 256));
    };

    ISSUE(0);
    WRITE(&xs[0]);
    ldwf(0, wfA);
    __syncthreads();

    for (int u = 0; u < 7; ++u) {
        unsigned* cur = &xs[(u & 1) * BUFW];
        if (u < 6) ISSUE(u + 1);         // loads fly under the tap loop

        #pragma unroll
        for (int v = 0; v < 7; ++v) {
            const int s = u * 7 + v;
            const int sp = (s < 48) ? s + 1 : 48;
            if (s & 1) ldwf(sp, wfA); else ldwf(sp, wfB);
            const bf16x8* cw = (s & 1) ? wfB : wfA;

            bf16x8 xf[4];
            #pragma unroll
            for (int pf = 0; pf < 4; ++pf) {
                const int scol = pf * 16 + l15 + 2 * v + 2;
                xf[pf] = *(const bf16x8*)((const unsigned short*)cur
                           + (ri * 80 + scol) * CELLS + quad * 8);
            }
            #pragma unroll
            for (int of = 0; of < 4; ++of)
                #pragma unroll
                for (int pf = 0; pf < 4; ++pf)
                    acc[of][pf] = __builtin_amdgcn_mfma_f32_16x16x32_bf16(
                        cw[of], xf[pf], acc[of][pf], 0, 0, 0);
        }

        if (u < 6) WRITE(&xs[((u + 1) & 1) * BUFW]);
        __syncthreads();
    }

    unsigned short* Pb = P + (size_t)(kz * 4 + b) * (128 * 4096) + (size_t)(h0 + ri) * 64;
    #pragma unroll
    for (int of = 0; of < 4; ++of) {
        const int oc = oc_off + of * 16 + quad * 4;
        #pragma unroll
        for (int pf = 0; pf < 4; ++pf) {
            const int w = pf * 16 + l15;
            #pragma unroll
            for (int reg = 0; reg < 4; ++reg)
                Pb[(size_t)(oc + reg) * 4096 + w] = f2bf(acc[of][pf][reg]);
        }
    }
}

// ---------------------------------------------------------------------------
// FUSED: conv2 (1x1, 128->49) + b2 + softmax + 49-tap dilated gather.
// grid (64 h, 4 b) = 256 blocks; block 512.
// ---------------------------------------------------------------------------
__global__ __launch_bounds__(512, 2) void conv2_gather_kernel(
    const unsigned short* __restrict__ P, const float* __restrict__ w2,
    const float* __restrict__ b2, const float* __restrict__ b1,
    const float* __restrict__ x, float* __restrict__ out)
{
    __shared__ float k1s[64 * 140];   // 35,840 B
    __shared__ float k2s[64 * 56];    // 14,336 B
    __shared__ float as[NJ * 64];     // 12,544 B  (total 62,720 <= 64K)
    const int h = blockIdx.x, b = blockIdx.y;
    const int t = threadIdx.x;

    for (int f = t; f < OC1 * 64; f += 512) {
        int w = f & 63, oc = f >> 6;
        float s = b1[oc];
        #pragma unroll
        for (int kzi = 0; kzi < KZ; ++kzi) {
            unsigned u = P[(((size_t)(kzi * 4 + b) * 128 + oc) * 64 + h) * 64 + w];
            s += __uint_as_float(u << 16);
        }
        k1s[w * 140 + oc] = s;
    }
    __syncthreads();

    const int w = t & 63, jg = t >> 6;
    float accj[7];
    if (jg < 7) {
        #pragma unroll
        for (int jj = 0; jj < 7; ++jj) accj[jj] = b2[7 * jg + jj];
        const float4* kv = (const float4*)&k1s[w * 140];
        for (int oc4 = 0; oc4 < 32; ++oc4) {
            float4 v = kv[oc4];
            #pragma unroll
            for (int jj = 0; jj < 7; ++jj) {
                const float* wr = w2 + (size_t)(7 * jg + jj) * OC1 + 4 * oc4;
                accj[jj] += v.x * wr[0] + v.y * wr[1] + v.z * wr[2] + v.w * wr[3];
            }
        }
        #pragma unroll
        for (int jj = 0; jj < 7; ++jj) k2s[w * 56 + 7 * jg + jj] = accj[jj];
    } else {
        #pragma unroll
        for (int j = 49; j < 56; ++j) k2s[w * 56 + j] = -1e30f;
    }
    __syncthreads();

    float4 vv[13];
    const float4* k2v = (const float4*)&k2s[w * 56];
    float m = -1e30f;
    #pragma unroll
    for (int i = 0; i < 13; ++i) {
        vv[i] = k2v[i];
        m = fmaxf(m, fmaxf(fmaxf(vv[i].x, vv[i].y), fmaxf(vv[i].z, vv[i].w)));
    }
    float s = 0.f;
    #pragma unroll
    for (int i = 0; i < 13; ++i) {
        s += __expf(vv[i].x - m) + __expf(vv[i].y - m)
           + __expf(vv[i].z - m) + __expf(vv[i].w - m);
    }
    const float inv = 1.f / s;
    if (jg < 7) {
        #pragma unroll
        for (int jj = 0; jj < 7; ++jj)
            as[(7 * jg + jj) * 64 + w] = __expf(accj[jj] - m) * inv;
    }
    __syncthreads();

    // gather: thread = (wp 16) x (cs 32); 4 passes cover 256 channels.
    const int wp = t & 15, cs = t >> 4;
    const int w0 = wp * 4;
    float* outb = out + (size_t)b * CIN * 4096 + (size_t)h * 64 + w0;

    for (int pass = 0; pass < 4; ++pass) {
        const int c0 = pass * 64 + cs * 2;
        const float* xb = x + (size_t)(b * CIN + c0) * 4096;
        float ac[2][4];
        #pragma unroll
        for (int c = 0; c < 2; ++c)
            #pragma unroll
            for (int wi = 0; wi < 4; ++wi) ac[c][wi] = 0.f;

        #pragma unroll
        for (int u = 0; u < 7; ++u) {
            const int row = h + 2 * u - 6;
            if ((unsigned)row >= 64u) continue;
            float xr[2][20];
            #pragma unroll
            for (int c = 0; c < 2; ++c) {
                const float4* rp = (const float4*)(xb + (size_t)c * 4096 + row * 64);
                #pragma unroll
                for (int j = 0; j < 5; ++j) {
                    const int i4 = wp - 2 + j;
                    float4 g = make_float4(0.f, 0.f, 0.f, 0.f);
                    if ((unsigned)i4 < 16u) g = rp[i4];
                    xr[c][4 * j + 0] = g.x; xr[c][4 * j + 1] = g.y;
                    xr[c][4 * j + 2] = g.z; xr[c][4 * j + 3] = g.w;
                }
            }
            #pragma unroll
            for (int v = 0; v < 7; ++v) {
                const float4 a4 = *(const float4*)&as[(u * 7 + v) * 64 + w0];
                const float av[4] = {a4.x, a4.y, a4.z, a4.w};
                #pragma unroll
                for (int wi = 0; wi < 4; ++wi)
                    #pragma unroll
                    for (int c = 0; c < 2; ++c)
                        ac[c][wi] += av[wi] * xr[c][wi + 2 * v + 2];
            }
        }
        #pragma unroll
        for (int c = 0; c < 2; ++c) {
            float4 st = make_float4(ac[c][0], ac[c][1], ac[c][2], ac[c][3]);
            *(float4*)&outb[(size_t)(c0 + c) * 4096] = st;
        }
    }
}

// ---------------------------------------------------------------------------
// ws: w1t bf16 3,211,264 B | P bf16 [8][4][128][4096] = 33,554,432 B (~36.8 MB)
// ---------------------------------------------------------------------------
extern "C" void kernel_launch(void* const* d_in, const int* in_sizes, int n_in,
                              void* d_out, int out_size, void* d_ws, size_t ws_size,
                              hipStream_t stream) {
    const float* x  = (const float*)d_in[0];
    const float* w1 = (const float*)d_in[1];
    const float* b1 = (const float*)d_in[2];
    const float* w2 = (const float*)d_in[3];
    const float* b2 = (const float*)d_in[4];
    float* out = (float*)d_out;

    unsigned short* w1t = (unsigned short*)d_ws;
    unsigned short* P   = (unsigned short*)((char*)d_ws + 3211264);

    wtrans_kernel<<<128, 256, 0, stream>>>(w1, w1t);
    conv1_mfma_kernel<<<dim3(32, KZ, 4), 256, 0, stream>>>(x, w1t, P);
    conv2_gather_kernel<<<dim3(HW, 4), 512, 0, stream>>>(P, w2, b2, b1, x, out);
}

// Round 8
// 220.716 us; speedup vs baseline: 2.3210x; 1.7460x over previous
//
#include <hip/hip_runtime.h>

#define HW 64
#define CIN 256
#define OC1 128
#define NJ 49
#define KZ 8                 // K-split: each conv1 block does 32 ic x 49 taps
#define CELLS 56             // shorts per (row,col) cell: 32 ic + 24 pad (112B, 16B-mult)
#define CELLW 28             // words per cell (stride 28 mod 32 -> 8 distinct write banks)
#define BUFW (2 * 80 * CELLW)   // 4480 words = 17,920 B per buffer

typedef short bf16x8 __attribute__((ext_vector_type(8)));
typedef float f32x4 __attribute__((ext_vector_type(4)));

__device__ __forceinline__ unsigned f2bf_pack(float a, float b) {
    unsigned ua = __float_as_uint(a);
    ua += 0x7FFF + ((ua >> 16) & 1);
    unsigned ub = __float_as_uint(b);
    ub += 0x7FFF + ((ub >> 16) & 1);
    return (ua >> 16) | (ub & 0xFFFF0000u);
}

__device__ __forceinline__ unsigned short f2bf(float a) {
    unsigned u = __float_as_uint(a);
    u += 0x7FFF + ((u >> 16) & 1);
    return (unsigned short)(u >> 16);
}

// ---------------------------------------------------------------------------
// w1 fp32 [128 oc][256 ic][49 tap] -> w1t bf16 [49][128 oc][256 ic]
// 256 blocks: (oc, ic-half).
// ---------------------------------------------------------------------------
__global__ __launch_bounds__(256) void wtrans_kernel(const float* __restrict__ w1,
                                                     unsigned short* __restrict__ w1t) {
    __shared__ float ws[128 * 49];    // [ic-half 128][tap 49]
    const int oc = blockIdx.x >> 1, ih = blockIdx.x & 1;
    const float4* src = (const float4*)(w1 + ((size_t)oc * 256 + ih * 128) * 49);
    for (int f = threadIdx.x; f < 1568; f += 256)
        *(float4*)&ws[4 * f] = src[f];
    __syncthreads();
    for (int k = threadIdx.x; k < 128 * 49; k += 256) {
        int tap = k / 128, ic = k - tap * 128;   // stride 49 mod 32 = 17: conflict-free
        w1t[((size_t)tap * 128 + oc) * 256 + ih * 128 + ic] = f2bf(ws[ic * 49 + tap]);
    }
}

// ---------------------------------------------------------------------------
// conv1 implicit GEMM, bf16 MFMA 16x16x32, KZ=8.
// grid (32 hp, 8 kz, 4 b) = 1024 blocks; block 256 = 4 waves; wave 64oc x 64px.
// Staging: global loads ISSUEd at u-start into packed regs, taps overlap the
// latency, LDS WRITE into the other buffer after the taps; 1 barrier per u.
// Weight fragments loaded INLINE per tap (wf ping-pong spilled in R6/R7:
// 32 extra live VGPRs pushed past budget -> 460 MB scratch traffic).
// P bf16 [kz][b][oc][h][w] partials.
// ---------------------------------------------------------------------------
__global__ __launch_bounds__(256) void conv1_mfma_kernel(
    const float* __restrict__ x, const unsigned short* __restrict__ w1t,
    unsigned short* __restrict__ P)
{
    __shared__ unsigned xs[2 * BUFW];   // 35,840 B

    const int hp = blockIdx.x, kz = blockIdx.y, b = blockIdx.z;
    const int h0 = hp * 2;
    const int t = threadIdx.x;
    const int lane = t & 63, wv = t >> 6;
    const int oc_off = (wv & 1) * 64;
    const int ri = wv >> 1;             // wave-uniform pixel row (0/1)
    const int l15 = lane & 15, quad = lane >> 4;

    f32x4 acc[4][4];
    #pragma unroll
    for (int i = 0; i < 4; ++i)
        #pragma unroll
        for (int j = 0; j < 4; ++j) acc[i][j] = (f32x4){0.f, 0.f, 0.f, 0.f};

    const float* xb = x + ((size_t)b * CIN + kz * 32) * 4096;
    const unsigned short* wbase = w1t + (size_t)(oc_off + l15) * 256 + kz * 32 + quad * 8;

    // 5 slots/thread: f = t + 256*i in [0,1280) -> (row 2, icq 8, col 80)
    uint2 pk[5];

    auto ISSUE = [&](int u) {           // global loads -> packed regs
        #pragma unroll
        for (int i = 0; i < 5; ++i) {
            int f = t + i * 256;
            int row = f / 640, rem = f - row * 640;
            int icq = rem / 80, col = rem - icq * 80;
            int r = h0 + row + 2 * u - 6;
            int c = col - 8;
            float v0 = 0.f, v1 = 0.f, v2 = 0.f, v3 = 0.f;
            if ((unsigned)r < 64u && (unsigned)c < 64u) {
                const float* p = xb + (size_t)(4 * icq) * 4096 + r * 64 + c;
                v0 = p[0]; v1 = p[4096]; v2 = p[8192]; v3 = p[12288];
            }
            pk[i] = make_uint2(f2bf_pack(v0, v1), f2bf_pack(v2, v3));
        }
    };
    auto WRITE = [&](unsigned* buf) {    // regs -> LDS (b64 per slot)
        #pragma unroll
        for (int i = 0; i < 5; ++i) {
            int f = t + i * 256;
            int row = f / 640, rem = f - row * 640;
            int icq = rem / 80, col = rem - icq * 80;
            *(uint2*)&buf[(row * 80 + col) * CELLW + 2 * icq] = pk[i];
        }
    };

    ISSUE(0);
    WRITE(&xs[0]);
    __syncthreads();

    for (int u = 0; u < 7; ++u) {
        unsigned* cur = &xs[(u & 1) * BUFW];
        if (u < 6) ISSUE(u + 1);         // loads fly under the tap loop

        #pragma unroll
        for (int v = 0; v < 7; ++v) {
            const int s = u * 7 + v;
            // wf loads issued first: 16 MFMA + 4 ds_reads of cover below
            const unsigned short* wp = wbase + (size_t)s * (128 * 256);
            bf16x8 wf[4];
            #pragma unroll
            for (int of = 0; of < 4; ++of)
                wf[of] = *(const bf16x8*)(wp + of * (16 * 256));

            bf16x8 xf[4];
            #pragma unroll
            for (int pf = 0; pf < 4; ++pf) {
                const int scol = pf * 16 + l15 + 2 * v + 2;
                xf[pf] = *(const bf16x8*)((const unsigned short*)cur
                           + (ri * 80 + scol) * CELLS + quad * 8);
            }
            #pragma unroll
            for (int of = 0; of < 4; ++of)
                #pragma unroll
                for (int pf = 0; pf < 4; ++pf)
                    acc[of][pf] = __builtin_amdgcn_mfma_f32_16x16x32_bf16(
                        wf[of], xf[pf], acc[of][pf], 0, 0, 0);
        }

        if (u < 6) WRITE(&xs[((u + 1) & 1) * BUFW]);
        __syncthreads();
    }

    unsigned short* Pb = P + (size_t)(kz * 4 + b) * (128 * 4096) + (size_t)(h0 + ri) * 64;
    #pragma unroll
    for (int of = 0; of < 4; ++of) {
        const int oc = oc_off + of * 16 + quad * 4;
        #pragma unroll
        for (int pf = 0; pf < 4; ++pf) {
            const int w = pf * 16 + l15;
            #pragma unroll
            for (int reg = 0; reg < 4; ++reg)
                Pb[(size_t)(oc + reg) * 4096 + w] = f2bf(acc[of][pf][reg]);
        }
    }
}

// ---------------------------------------------------------------------------
// FUSED: conv2 (1x1, 128->49) + b2 + softmax + 49-tap dilated gather.
// grid (64 h, 4 b) = 256 blocks; block 512.
// ---------------------------------------------------------------------------
__global__ __launch_bounds__(512, 2) void conv2_gather_kernel(
    const unsigned short* __restrict__ P, const float* __restrict__ w2,
    const float* __restrict__ b2, const float* __restrict__ b1,
    const float* __restrict__ x, float* __restrict__ out)
{
    __shared__ float k1s[64 * 140];   // 35,840 B
    __shared__ float k2s[64 * 56];    // 14,336 B
    __shared__ float as[NJ * 64];     // 12,544 B  (total 62,720 <= 64K)
    const int h = blockIdx.x, b = blockIdx.y;
    const int t = threadIdx.x;

    for (int f = t; f < OC1 * 64; f += 512) {
        int w = f & 63, oc = f >> 6;
        float s = b1[oc];
        #pragma unroll
        for (int kzi = 0; kzi < KZ; ++kzi) {
            unsigned u = P[(((size_t)(kzi * 4 + b) * 128 + oc) * 64 + h) * 64 + w];
            s += __uint_as_float(u << 16);
        }
        k1s[w * 140 + oc] = s;
    }
    __syncthreads();

    const int w = t & 63, jg = t >> 6;
    float accj[7];
    if (jg < 7) {
        #pragma unroll
        for (int jj = 0; jj < 7; ++jj) accj[jj] = b2[7 * jg + jj];
        const float4* kv = (const float4*)&k1s[w * 140];
        for (int oc4 = 0; oc4 < 32; ++oc4) {
            float4 v = kv[oc4];
            #pragma unroll
            for (int jj = 0; jj < 7; ++jj) {
                const float* wr = w2 + (size_t)(7 * jg + jj) * OC1 + 4 * oc4;
                accj[jj] += v.x * wr[0] + v.y * wr[1] + v.z * wr[2] + v.w * wr[3];
            }
        }
        #pragma unroll
        for (int jj = 0; jj < 7; ++jj) k2s[w * 56 + 7 * jg + jj] = accj[jj];
    } else {
        #pragma unroll
        for (int j = 49; j < 56; ++j) k2s[w * 56 + j] = -1e30f;
    }
    __syncthreads();

    float4 vv[13];
    const float4* k2v = (const float4*)&k2s[w * 56];
    float m = -1e30f;
    #pragma unroll
    for (int i = 0; i < 13; ++i) {
        vv[i] = k2v[i];
        m = fmaxf(m, fmaxf(fmaxf(vv[i].x, vv[i].y), fmaxf(vv[i].z, vv[i].w)));
    }
    float s = 0.f;
    #pragma unroll
    for (int i = 0; i < 13; ++i) {
        s += __expf(vv[i].x - m) + __expf(vv[i].y - m)
           + __expf(vv[i].z - m) + __expf(vv[i].w - m);
    }
    const float inv = 1.f / s;
    if (jg < 7) {
        #pragma unroll
        for (int jj = 0; jj < 7; ++jj)
            as[(7 * jg + jj) * 64 + w] = __expf(accj[jj] - m) * inv;
    }
    __syncthreads();

    // gather: thread = (wp 16) x (cs 32); 4 passes cover 256 channels.
    const int wp = t & 15, cs = t >> 4;
    const int w0 = wp * 4;
    float* outb = out + (size_t)b * CIN * 4096 + (size_t)h * 64 + w0;

    for (int pass = 0; pass < 4; ++pass) {
        const int c0 = pass * 64 + cs * 2;
        const float* xb = x + (size_t)(b * CIN + c0) * 4096;
        float ac[2][4];
        #pragma unroll
        for (int c = 0; c < 2; ++c)
            #pragma unroll
            for (int wi = 0; wi < 4; ++wi) ac[c][wi] = 0.f;

        #pragma unroll
        for (int u = 0; u < 7; ++u) {
            const int row = h + 2 * u - 6;
            if ((unsigned)row >= 64u) continue;
            float xr[2][20];
            #pragma unroll
            for (int c = 0; c < 2; ++c) {
                const float4* rp = (const float4*)(xb + (size_t)c * 4096 + row * 64);
                #pragma unroll
                for (int j = 0; j < 5; ++j) {
                    const int i4 = wp - 2 + j;
                    float4 g = make_float4(0.f, 0.f, 0.f, 0.f);
                    if ((unsigned)i4 < 16u) g = rp[i4];
                    xr[c][4 * j + 0] = g.x; xr[c][4 * j + 1] = g.y;
                    xr[c][4 * j + 2] = g.z; xr[c][4 * j + 3] = g.w;
                }
            }
            #pragma unroll
            for (int v = 0; v < 7; ++v) {
                const float4 a4 = *(const float4*)&as[(u * 7 + v) * 64 + w0];
                const float av[4] = {a4.x, a4.y, a4.z, a4.w};
                #pragma unroll
                for (int wi = 0; wi < 4; ++wi)
                    #pragma unroll
                    for (int c = 0; c < 2; ++c)
                        ac[c][wi] += av[wi] * xr[c][wi + 2 * v + 2];
            }
        }
        #pragma unroll
        for (int c = 0; c < 2; ++c) {
            float4 st = make_float4(ac[c][0], ac[c][1], ac[c][2], ac[c][3]);
            *(float4*)&outb[(size_t)(c0 + c) * 4096] = st;
        }
    }
}

// ---------------------------------------------------------------------------
// ws: w1t bf16 3,211,264 B | P bf16 [8][4][128][4096] = 33,554,432 B (~36.8 MB)
// ---------------------------------------------------------------------------
extern "C" void kernel_launch(void* const* d_in, const int* in_sizes, int n_in,
                              void* d_out, int out_size, void* d_ws, size_t ws_size,
                              hipStream_t stream) {
    const float* x  = (const float*)d_in[0];
    const float* w1 = (const float*)d_in[1];
    const float* b1 = (const float*)d_in[2];
    const float* w2 = (const float*)d_in[3];
    const float* b2 = (const float*)d_in[4];
    float* out = (float*)d_out;

    unsigned short* w1t = (unsigned short*)d_ws;
    unsigned short* P   = (unsigned short*)((char*)d_ws + 3211264);

    wtrans_kernel<<<256, 256, 0, stream>>>(w1, w1t);
    conv1_mfma_kernel<<<dim3(32, KZ, 4), 256, 0, stream>>>(x, w1t, P);
    conv2_gather_kernel<<<dim3(HW, 4), 512, 0, stream>>>(P, w2, b2, b1, x, out);
}